// Round 6
// baseline (112.283 us; speedup 1.0000x reference)
//
#include <hip/hip_runtime.h>
#include <math.h>

#define MPTS 8192
#define DIMS 32
#define QB   64      // queries per block
#define NW   16      // waves per block (1024 threads)
#define NEGI -3.4e38f

typedef __bf16 bf16x8 __attribute__((ext_vector_type(8)));
typedef float  f32x4  __attribute__((ext_vector_type(4)));

// Insert v into sorted-DESCENDING top-4 (t0>=t1>=t2>=t3): 1 max + 3 med3.
// Idempotent for v <= t3 (chain unchanged) -> safe under wave-uniform any() guards.
__device__ __forceinline__ void top4L_insert(float v, float& t0, float& t1, float& t2, float& t3) {
    float n0 = fmaxf(t0, v);
    float n1 = __builtin_amdgcn_fmed3f(v, t0, t1);
    float n2 = __builtin_amdgcn_fmed3f(v, t1, t2);
    float n3 = __builtin_amdgcn_fmed3f(v, t2, t3);
    t0 = n0; t1 = n1; t2 = n2; t3 = n3;
}

// Merge two sorted-desc 4-lists -> sorted-desc top-4 (bitonic half-cleaner + merge, 12 ops).
__device__ __forceinline__ void top4_merge(float u0, float u1, float u2, float u3,
                                           float& t0, float& t1, float& t2, float& t3) {
    float m0 = fmaxf(t0, u3), m1 = fmaxf(t1, u2), m2 = fmaxf(t2, u1), m3 = fmaxf(t3, u0);
    float a = fmaxf(m0, m2), c = fminf(m0, m2);
    float b = fmaxf(m1, m3), d = fminf(m1, m3);
    t0 = fmaxf(a, b); t1 = fminf(a, b); t2 = fmaxf(c, d); t3 = fminf(c, d);
}

__device__ __forceinline__ unsigned short f32_to_bf16_rne(float x) {
    unsigned u = __float_as_uint(x);
    unsigned r = u + 0x7FFFu + ((u >> 16) & 1u);
    return (unsigned short)(r >> 16);
}

// K1: bf16 conversion of P,Q + norms pre-scaled by -0.5 ( -|x|^2/2 ). Also zeroes totals.
__global__ void prep_kernel(const float* __restrict__ P, const float* __restrict__ Q,
                            unsigned short* __restrict__ Phi, unsigned short* __restrict__ Qhi,
                            float* __restrict__ normP, float* __restrict__ normQ,
                            int* __restrict__ tots) {
    if (blockIdx.x == 0 && threadIdx.x < 2) tots[threadIdx.x] = 0;
    int t = blockIdx.x * 256 + threadIdx.x;          // 0 .. 65535
    int mat = t >> 15;                               // 0 = P, 1 = Q
    int idx = t & 32767;
    int r = idx >> 2, seg = idx & 3;                 // 8 elements per thread
    const float* X = mat ? Q : P;
    unsigned short* Xhi = mat ? Qhi : Phi;
    float* nX = mat ? normQ : normP;

    const float* src = X + (size_t)r * DIMS + seg * 8;
    float4 v0 = *(const float4*)(src);
    float4 v1 = *(const float4*)(src + 4);
    float f[8] = {v0.x, v0.y, v0.z, v0.w, v1.x, v1.y, v1.z, v1.w};

    float p = 0.f;
#pragma unroll
    for (int k = 0; k < 8; ++k) p = fmaf(f[k], f[k], p);
    p += __shfl_xor(p, 1);
    p += __shfl_xor(p, 2);      // seg groups of 4 are lane-aligned
    if (seg == 0) nX[r] = -0.5f * p;

    unsigned short h[8];
#pragma unroll
    for (int k = 0; k < 8; ++k) h[k] = f32_to_bf16_rne(f[k]);
    uint4 ph;
    ph.x = (unsigned)h[0] | ((unsigned)h[1] << 16);
    ph.y = (unsigned)h[2] | ((unsigned)h[3] << 16);
    ph.z = (unsigned)h[4] | ((unsigned)h[5] << 16);
    ph.w = (unsigned)h[6] | ((unsigned)h[7] << 16);
    *(uint4*)(Xhi + (size_t)r * DIMS + seg * 8) = ph;
}

// K2: fused 3-pass knn+count. grid (128, 2 dirs), 16 waves, 1 block/CU.
// Pass A: per-chain running MAX over Y (v_max3, 0.5 op/pair) -> merge -> tau0 =
//   4th-largest of the 64 chunk maxima per query (provable lower bound on the
//   4th-largest s: the 4 chunks achieving the top-4 maxima each hold a value >= tau0).
// Pass B: rescan Y, exact top-4 with wave-uniform __any(v>=tau0) branch guards
//   (~94% of steps skip; inserts idempotent for losers) -> bit-exact v4 -> nu, tau.
// Pass C: count s >= tau over X, same __any guard (counts sparse, ~96% skip).
// s-domain: s = dot - na/2 (larger == closer; per-query shift constant).
__global__ __launch_bounds__(1024, 4)
void fused_kernel(const unsigned short* __restrict__ Phi, const unsigned short* __restrict__ Qhi,
                  const float* __restrict__ normP, const float* __restrict__ normQ,
                  float* __restrict__ nusqP, float* __restrict__ nusqQ,
                  int* __restrict__ countP, int* __restrict__ countQ,
                  int* __restrict__ tots) {
    __shared__ float4 ldsM[NW * QB];     // 16 KB: [wave][query] top-4
    __shared__ int    ldsC[NW * QB];     //  4 KB: [wave][query] counts
    __shared__ float  ldsTau0[QB];
    __shared__ float  ldsTau[QB];
    const unsigned short *Yhi, *Xhi; const float *nY, *nX; float* nusqOut;
    int* cntOut; int* totOut;
    if (blockIdx.y == 0) { Yhi = Qhi; nY = normQ; Xhi = Phi; nX = normP;
                           nusqOut = nusqQ; cntOut = countQ; totOut = &tots[1]; } // k_p for div_p
    else                 { Yhi = Phi; nY = normP; Xhi = Qhi; nX = normQ;
                           nusqOut = nusqP; cntOut = countP; totOut = &tots[0]; }
    const int tid = threadIdx.x;
    const int w = tid >> 6, l = tid & 63, q = l & 15, quad = l >> 4;
    const int q0 = blockIdx.x * QB;

    // 4 B-frags: query rows q0 + 16*b + q; k-octet = quad
    bf16x8 bh[4];
#pragma unroll
    for (int b = 0; b < 4; ++b)
        bh[b] = *(const bf16x8*)(Yhi + (size_t)(q0 + b * 16 + q) * DIMS + quad * 8);

    // ---------- pass A: per-chain max over Y ----------
    float mx[4];
#pragma unroll
    for (int b = 0; b < 4; ++b) mx[b] = NEGI;
    {
        const unsigned short* pH = Yhi + ((size_t)(w * 512) + q) * DIMS + quad * 8;
        const float* pN = nY + w * 512 + quad * 4;
        for (int i = 0; i < 16; ++i) {
            bf16x8 ah0 = *(const bf16x8*)(pH);
            bf16x8 ah1 = *(const bf16x8*)(pH + 16 * DIMS);
            float4 nA0 = *(const float4*)(pN);
            float4 nA1 = *(const float4*)(pN + 16);
            pH += 32 * DIMS; pN += 32;
            f32x4 c0v = {nA0.x, nA0.y, nA0.z, nA0.w};
            f32x4 c1v = {nA1.x, nA1.y, nA1.z, nA1.w};
#pragma unroll
            for (int b = 0; b < 4; ++b) {
                f32x4 a0 = __builtin_amdgcn_mfma_f32_16x16x32_bf16(ah0, bh[b], c0v, 0, 0, 0);
                f32x4 a1 = __builtin_amdgcn_mfma_f32_16x16x32_bf16(ah1, bh[b], c1v, 0, 0, 0);
                mx[b] = fmaxf(fmaxf(mx[b], a0[0]), a0[1]);   // v_max3
                mx[b] = fmaxf(fmaxf(mx[b], a0[2]), a0[3]);
                mx[b] = fmaxf(fmaxf(mx[b], a1[0]), a1[1]);
                mx[b] = fmaxf(fmaxf(mx[b], a1[2]), a1[3]);
            }
        }
    }
    // quad butterfly on single maxima -> per-wave sorted-4 of its 4 chunk maxima
#pragma unroll
    for (int b = 0; b < 4; ++b) {
        float u = __shfl_xor(mx[b], 16);
        float t0 = fmaxf(mx[b], u), t1 = fminf(mx[b], u), t2 = NEGI, t3 = NEGI;
        float u0 = __shfl_xor(t0, 32), u1 = __shfl_xor(t1, 32);
        top4_merge(u0, u1, NEGI, NEGI, t0, t1, t2, t3);
        if (quad == 0)
            ldsM[w * QB + q + b * 16] = make_float4(t0, t1, t2, t3);
    }
    __syncthreads();
    if (tid < QB) {                      // 4th-largest of 64 chunk maxima = tau0
        float a0 = NEGI, a1 = NEGI, a2 = NEGI, a3 = NEGI;
#pragma unroll
        for (int u = 0; u < NW; ++u) {
            float4 v = ldsM[u * QB + tid];
            top4L_insert(v.x, a0, a1, a2, a3);
            top4L_insert(v.y, a0, a1, a2, a3);
            top4L_insert(v.z, a0, a1, a2, a3);
            top4L_insert(v.w, a0, a1, a2, a3);
        }
        ldsTau0[tid] = a3;
    }
    __syncthreads();
    float tau0[4];
#pragma unroll
    for (int b = 0; b < 4; ++b) tau0[b] = ldsTau0[q + b * 16];

    // ---------- pass B: filtered exact top-4 over Y ----------
    float t0[4], t1[4], t2[4], t3[4];
#pragma unroll
    for (int b = 0; b < 4; ++b) t0[b] = t1[b] = t2[b] = t3[b] = NEGI;
    {
        const unsigned short* pH = Yhi + ((size_t)(w * 512) + q) * DIMS + quad * 8;
        const float* pN = nY + w * 512 + quad * 4;
#pragma unroll 2
        for (int i = 0; i < 16; ++i) {
            bf16x8 ah0 = *(const bf16x8*)(pH);
            bf16x8 ah1 = *(const bf16x8*)(pH + 16 * DIMS);
            float4 nA0 = *(const float4*)(pN);
            float4 nA1 = *(const float4*)(pN + 16);
            pH += 32 * DIMS; pN += 32;
            f32x4 c0v = {nA0.x, nA0.y, nA0.z, nA0.w};
            f32x4 c1v = {nA1.x, nA1.y, nA1.z, nA1.w};
#pragma unroll
            for (int b = 0; b < 4; ++b) {
                f32x4 a0 = __builtin_amdgcn_mfma_f32_16x16x32_bf16(ah0, bh[b], c0v, 0, 0, 0);
                f32x4 a1 = __builtin_amdgcn_mfma_f32_16x16x32_bf16(ah1, bh[b], c1v, 0, 0, 0);
#pragma unroll
                for (int r = 0; r < 4; ++r) {
                    if (__any(a0[r] >= tau0[b]))
                        top4L_insert(a0[r], t0[b], t1[b], t2[b], t3[b]);
                    if (__any(a1[r] >= tau0[b]))
                        top4L_insert(a1[r], t0[b], t1[b], t2[b], t3[b]);
                }
            }
        }
    }
    // in-register quad merge (lanes q, q+16, q+32, q+48 hold disjoint candidate rows)
#pragma unroll
    for (int b = 0; b < 4; ++b) {
        float u0 = __shfl_xor(t0[b], 16), u1 = __shfl_xor(t1[b], 16);
        float u2 = __shfl_xor(t2[b], 16), u3 = __shfl_xor(t3[b], 16);
        top4_merge(u0, u1, u2, u3, t0[b], t1[b], t2[b], t3[b]);
        u0 = __shfl_xor(t0[b], 32); u1 = __shfl_xor(t1[b], 32);
        u2 = __shfl_xor(t2[b], 32); u3 = __shfl_xor(t3[b], 32);
        top4_merge(u0, u1, u2, u3, t0[b], t1[b], t2[b], t3[b]);
        if (quad == 0)
            ldsM[w * QB + q + b * 16] = make_float4(t0[b], t1[b], t2[b], t3[b]);
    }
    __syncthreads();
    // block merge: 16 wave-lists per query -> exact v4 -> nu, tau
    if (tid < QB) {
        float a0 = NEGI, a1 = NEGI, a2 = NEGI, a3 = NEGI;
#pragma unroll
        for (int u = 0; u < NW; ++u) {
            float4 v = ldsM[u * QB + tid];
            top4L_insert(v.x, a0, a1, a2, a3);
            top4L_insert(v.y, a0, a1, a2, a3);
            top4L_insert(v.z, a0, a1, a2, a3);
            top4L_insert(v.w, a0, a1, a2, a3);
        }
        float nb = -2.0f * nY[q0 + tid];               // |y|^2
        float nu2 = fmaxf(nb - 2.0f * a3, 1e-12f);     // sq-domain nu^2, clamped
        nusqOut[q0 + tid] = nu2;
        ldsTau[tid] = 0.5f * (nb - nu2);               // s-domain threshold
    }
    __syncthreads();
    float tau[4];
#pragma unroll
    for (int b = 0; b < 4; ++b) tau[b] = ldsTau[q + b * 16];

    // ---------- pass C: count over X ----------
    int cnt[4] = {0, 0, 0, 0};
    {
        const unsigned short* pH = Xhi + ((size_t)(w * 512) + q) * DIMS + quad * 8;
        const float* pN = nX + w * 512 + quad * 4;
#pragma unroll 2
        for (int i = 0; i < 16; ++i) {
            bf16x8 ah0 = *(const bf16x8*)(pH);
            bf16x8 ah1 = *(const bf16x8*)(pH + 16 * DIMS);
            float4 nA0 = *(const float4*)(pN);
            float4 nA1 = *(const float4*)(pN + 16);
            pH += 32 * DIMS; pN += 32;
            f32x4 c0v = {nA0.x, nA0.y, nA0.z, nA0.w};
            f32x4 c1v = {nA1.x, nA1.y, nA1.z, nA1.w};
#pragma unroll
            for (int b = 0; b < 4; ++b) {
                f32x4 a0 = __builtin_amdgcn_mfma_f32_16x16x32_bf16(ah0, bh[b], c0v, 0, 0, 0);
                f32x4 a1 = __builtin_amdgcn_mfma_f32_16x16x32_bf16(ah1, bh[b], c1v, 0, 0, 0);
#pragma unroll
                for (int r = 0; r < 4; ++r) {
                    if (__any(a0[r] >= tau[b])) cnt[b] += (a0[r] >= tau[b]) ? 1 : 0;
                    if (__any(a1[r] >= tau[b])) cnt[b] += (a1[r] >= tau[b]) ? 1 : 0;
                }
            }
        }
    }
    // quad reduce in-register, then [wave][query] LDS
#pragma unroll
    for (int b = 0; b < 4; ++b) {
        int c = cnt[b] + __shfl_xor(cnt[b], 16);
        c += __shfl_xor(c, 32);
        if (quad == 0) ldsC[w * QB + q + b * 16] = c;
    }
    __syncthreads();
    if (tid < QB) {
        int s = 0;
#pragma unroll
        for (int u = 0; u < NW; ++u) s += ldsC[u * QB + tid];
        cntOut[q0 + tid] = s;
        int rsum = s;                                   // block total (wave 0)
        rsum += __shfl_xor(rsum, 1);
        rsum += __shfl_xor(rsum, 2);
        rsum += __shfl_xor(rsum, 4);
        rsum += __shfl_xor(rsum, 8);
        rsum += __shfl_xor(rsum, 16);
        rsum += __shfl_xor(rsum, 32);
        if (tid == 0) atomicAdd(totOut, rsum);          // exact integer sum
    }
}

// K3a: epilogue partials, 16 blocks x 512 thr (one j per thread). Per-block double
// partial sums are deterministic (fixed shuffle-tree order); written to dparts.
__global__ __launch_bounds__(512)
void final_partial(const int* __restrict__ countP, const int* __restrict__ countQ,
                   const float* __restrict__ nusqP, const float* __restrict__ nusqQ,
                   const int* __restrict__ tots, double* __restrict__ dparts) {
    __shared__ double rdQ[8], rdP[8];
    const int tid = threadIdx.x, b = blockIdx.x;
    const int w = tid >> 6, l = tid & 63;
    const int j = b * 512 + tid;

    const float kq_term = 3.0f / 24576.0f;
    float kpQ = (float)tots[1] + 1e-20f;
    float kpP = (float)tots[0] + 1e-20f;
    double rQ, rP;
    {
        float nu = sqrtf(nusqQ[j]);
        float x = nu * nu; x *= x; x *= x; x *= x; x *= x;   // nu^32
        float inv = 1.0f / (x + 1e-20f);
        float p_den = ((float)countQ[j] / kpQ) * inv;
        p_den = fminf(fmaxf(p_den, 1e-20f), 1e10f);
        float q_den = kq_term * inv;
        q_den = fminf(fmaxf(q_den, 1e-20f), 1e10f);
        rQ = (double)((p_den / q_den) * kq_term);
    }
    {
        float nu = sqrtf(nusqP[j]);
        float x = nu * nu; x *= x; x *= x; x *= x; x *= x;
        float inv = 1.0f / (x + 1e-20f);
        float p_den = ((float)countP[j] / kpP) * inv;
        p_den = fminf(fmaxf(p_den, 1e-20f), 1e10f);
        float q_den = kq_term * inv;
        q_den = fminf(fmaxf(q_den, 1e-20f), 1e10f);
        rP = (double)((p_den / q_den) * kq_term);
    }
#pragma unroll
    for (int o = 32; o > 0; o >>= 1) { rQ += __shfl_down(rQ, o); rP += __shfl_down(rP, o); }
    if (l == 0) { rdQ[w] = rQ; rdP[w] = rP; }
    __syncthreads();
    if (tid == 0) {
        double RQ = 0.0, RP = 0.0;
#pragma unroll
        for (int u = 0; u < 8; ++u) { RQ += rdQ[u]; RP += rdP[u]; }
        dparts[b] = RQ; dparts[16 + b] = RP;
    }
}

// K3b: tiny reduce, fixed summation order.
__global__ void final_reduce(const double* __restrict__ dparts, float* __restrict__ out) {
    if (threadIdx.x == 0) {
        double RQ = 0.0, RP = 0.0;
#pragma unroll
        for (int u = 0; u < 16; ++u) RQ += dparts[u];
#pragma unroll
        for (int u = 0; u < 16; ++u) RP += dparts[16 + u];
        float divP = fmaxf(0.0f, logf((float)RQ));    // alpha=2 -> 1/(alpha-1)=1
        float divQ = fmaxf(0.0f, logf((float)RP));
        out[0] = fmaxf(divP, divQ);
    }
}

extern "C" void kernel_launch(void* const* d_in, const int* in_sizes, int n_in,
                              void* d_out, int out_size, void* d_ws, size_t ws_size,
                              hipStream_t stream) {
    const float* P = (const float*)d_in[0];
    const float* Q = (const float*)d_in[1];
    float* out = (float*)d_out;

    unsigned short* Phi = (unsigned short*)d_ws;
    unsigned short* Qhi = Phi + MPTS * DIMS;
    float* normP = (float*)(Qhi + MPTS * DIMS);
    float* normQ = normP + MPTS;
    float* nusqP = normQ + MPTS;
    float* nusqQ = nusqP + MPTS;
    int* countP  = (int*)(nusqQ + MPTS);
    int* countQ  = countP + MPTS;
    int* tots    = countQ + MPTS;                     // [0]=sum countP, [1]=sum countQ
    double* dparts = (double*)(tots + 2);             // 32 doubles (8B aligned)

    prep_kernel<<<256, 256, 0, stream>>>(P, Q, Phi, Qhi, normP, normQ, tots);
    fused_kernel<<<dim3(MPTS / QB, 2), 1024, 0, stream>>>(Phi, Qhi, normP, normQ,
                                                          nusqP, nusqQ, countP, countQ, tots);
    final_partial<<<16, 512, 0, stream>>>(countP, countQ, nusqP, nusqQ, tots, dparts);
    final_reduce<<<1, 64, 0, stream>>>(dparts, out);
}

// Round 7
// 105.753 us; speedup vs baseline: 1.0617x; 1.0617x over previous
//
#include <hip/hip_runtime.h>
#include <math.h>

#define MPTS 8192
#define DIMS 32
#define QB   64      // queries per block
#define NW   16      // waves per block (1024 threads)
#define NEGI -3.4e38f

typedef __bf16 bf16x8 __attribute__((ext_vector_type(8)));
typedef float  f32x4  __attribute__((ext_vector_type(4)));

// Insert v into sorted-DESCENDING top-4 (t0>=t1>=t2>=t3): 1 max + 3 med3.
__device__ __forceinline__ void top4L_insert(float v, float& t0, float& t1, float& t2, float& t3) {
    float n0 = fmaxf(t0, v);
    float n1 = __builtin_amdgcn_fmed3f(v, t0, t1);
    float n2 = __builtin_amdgcn_fmed3f(v, t1, t2);
    float n3 = __builtin_amdgcn_fmed3f(v, t2, t3);
    t0 = n0; t1 = n1; t2 = n2; t3 = n3;
}

// Merge two sorted-desc 4-lists -> sorted-desc top-4 (bitonic half-cleaner + merge, 12 ops).
__device__ __forceinline__ void top4_merge(float u0, float u1, float u2, float u3,
                                           float& t0, float& t1, float& t2, float& t3) {
    float m0 = fmaxf(t0, u3), m1 = fmaxf(t1, u2), m2 = fmaxf(t2, u1), m3 = fmaxf(t3, u0);
    float a = fmaxf(m0, m2), c = fminf(m0, m2);
    float b = fmaxf(m1, m3), d = fminf(m1, m3);
    t0 = fmaxf(a, b); t1 = fminf(a, b); t2 = fmaxf(c, d); t3 = fminf(c, d);
}

__device__ __forceinline__ unsigned short f32_to_bf16_rne(float x) {
    unsigned u = __float_as_uint(x);
    unsigned r = u + 0x7FFFu + ((u >> 16) & 1u);
    return (unsigned short)(r >> 16);
}

// K1: bf16 conversion of P,Q + norms pre-scaled by -0.5 ( -|x|^2/2 ).
// Also zeroes count totals and the final-kernel completion counter.
__global__ void prep_kernel(const float* __restrict__ P, const float* __restrict__ Q,
                            unsigned short* __restrict__ Phi, unsigned short* __restrict__ Qhi,
                            float* __restrict__ normP, float* __restrict__ normQ,
                            int* __restrict__ tots) {
    if (blockIdx.x == 0 && threadIdx.x < 3) tots[threadIdx.x] = 0;
    int t = blockIdx.x * 256 + threadIdx.x;          // 0 .. 65535
    int mat = t >> 15;                               // 0 = P, 1 = Q
    int idx = t & 32767;
    int r = idx >> 2, seg = idx & 3;                 // 8 elements per thread
    const float* X = mat ? Q : P;
    unsigned short* Xhi = mat ? Qhi : Phi;
    float* nX = mat ? normQ : normP;

    const float* src = X + (size_t)r * DIMS + seg * 8;
    float4 v0 = *(const float4*)(src);
    float4 v1 = *(const float4*)(src + 4);
    float f[8] = {v0.x, v0.y, v0.z, v0.w, v1.x, v1.y, v1.z, v1.w};

    float p = 0.f;
#pragma unroll
    for (int k = 0; k < 8; ++k) p = fmaf(f[k], f[k], p);
    p += __shfl_xor(p, 1);
    p += __shfl_xor(p, 2);      // seg groups of 4 are lane-aligned
    if (seg == 0) nX[r] = -0.5f * p;

    unsigned short h[8];
#pragma unroll
    for (int k = 0; k < 8; ++k) h[k] = f32_to_bf16_rne(f[k]);
    uint4 ph;
    ph.x = (unsigned)h[0] | ((unsigned)h[1] << 16);
    ph.y = (unsigned)h[2] | ((unsigned)h[3] << 16);
    ph.z = (unsigned)h[4] | ((unsigned)h[5] << 16);
    ph.w = (unsigned)h[6] | ((unsigned)h[7] << 16);
    *(uint4*)(Xhi + (size_t)r * DIMS + seg * 8) = ph;
}

// K2: fused 2-pass knn+count (best-measured body: plain loop, global norm loads,
// compiler scheduling — manual prefetch/unroll/LDS-norms all measured neutral-negative).
// grid (128, 2 dirs), 16 waves, 1 block/CU. Block owns 64 queries; lane holds 4
// B-frags (queries q+16b) -> 4 top-4 chains. Wave w scans rows [w*512,(w+1)*512):
// per iter 2 row loads feed 8 MFMAs -> 32 inserts. s-domain: s = dot - na/2
// (larger == closer). Quad-lists merged in-register via shfl_xor(16/32) + bitonic
// merge; pass 2 counts s >= tau; block totals atomicAdd'd (exact integer).
__global__ __launch_bounds__(1024, 4)
void fused_kernel(const unsigned short* __restrict__ Phi, const unsigned short* __restrict__ Qhi,
                  const float* __restrict__ normP, const float* __restrict__ normQ,
                  float* __restrict__ nusqP, float* __restrict__ nusqQ,
                  int* __restrict__ countP, int* __restrict__ countQ,
                  int* __restrict__ tots) {
    __shared__ float4 ldsM[NW * QB];     // 16 KB: [wave][query] top-4
    __shared__ int    ldsC[NW * QB];     //  4 KB: [wave][query] counts
    __shared__ float  ldsTau[QB];
    const unsigned short *Yhi, *Xhi; const float *nY, *nX; float* nusqOut;
    int* cntOut; int* totOut;
    if (blockIdx.y == 0) { Yhi = Qhi; nY = normQ; Xhi = Phi; nX = normP;
                           nusqOut = nusqQ; cntOut = countQ; totOut = &tots[1]; } // k_p for div_p
    else                 { Yhi = Phi; nY = normP; Xhi = Qhi; nX = normQ;
                           nusqOut = nusqP; cntOut = countP; totOut = &tots[0]; }
    const int tid = threadIdx.x;
    const int w = tid >> 6, l = tid & 63, q = l & 15, quad = l >> 4;
    const int q0 = blockIdx.x * QB;

    // 4 B-frags: query rows q0 + 16*b + q; k-octet = quad
    bf16x8 bh[4];
#pragma unroll
    for (int b = 0; b < 4; ++b)
        bh[b] = *(const bf16x8*)(Yhi + (size_t)(q0 + b * 16 + q) * DIMS + quad * 8);

    // ---------- pass 1: knn over Y ----------
    float t0[4], t1[4], t2[4], t3[4];
#pragma unroll
    for (int b = 0; b < 4; ++b) t0[b] = t1[b] = t2[b] = t3[b] = NEGI;
    {
        const unsigned short* pH = Yhi + ((size_t)(w * 512) + q) * DIMS + quad * 8;
        const float* pN = nY + w * 512 + quad * 4;
        for (int i = 0; i < 16; ++i) {
            bf16x8 ah0 = *(const bf16x8*)(pH);
            bf16x8 ah1 = *(const bf16x8*)(pH + 16 * DIMS);
            float4 nA0 = *(const float4*)(pN);
            float4 nA1 = *(const float4*)(pN + 16);
            pH += 32 * DIMS; pN += 32;
            f32x4 c0v = {nA0.x, nA0.y, nA0.z, nA0.w};
            f32x4 c1v = {nA1.x, nA1.y, nA1.z, nA1.w};
#pragma unroll
            for (int b = 0; b < 4; ++b) {
                f32x4 a0 = __builtin_amdgcn_mfma_f32_16x16x32_bf16(ah0, bh[b], c0v, 0, 0, 0);
                f32x4 a1 = __builtin_amdgcn_mfma_f32_16x16x32_bf16(ah1, bh[b], c1v, 0, 0, 0);
#pragma unroll
                for (int r = 0; r < 4; ++r) top4L_insert(a0[r], t0[b], t1[b], t2[b], t3[b]);
#pragma unroll
                for (int r = 0; r < 4; ++r) top4L_insert(a1[r], t0[b], t1[b], t2[b], t3[b]);
            }
        }
    }
    // in-register quad merge (lanes q, q+16, q+32, q+48 hold disjoint candidate rows)
#pragma unroll
    for (int b = 0; b < 4; ++b) {
        float u0 = __shfl_xor(t0[b], 16), u1 = __shfl_xor(t1[b], 16);
        float u2 = __shfl_xor(t2[b], 16), u3 = __shfl_xor(t3[b], 16);
        top4_merge(u0, u1, u2, u3, t0[b], t1[b], t2[b], t3[b]);
        u0 = __shfl_xor(t0[b], 32); u1 = __shfl_xor(t1[b], 32);
        u2 = __shfl_xor(t2[b], 32); u3 = __shfl_xor(t3[b], 32);
        top4_merge(u0, u1, u2, u3, t0[b], t1[b], t2[b], t3[b]);
        if (quad == 0)
            ldsM[w * QB + q + b * 16] = make_float4(t0[b], t1[b], t2[b], t3[b]);
    }
    __syncthreads();
    // block merge: 16 wave-lists per query -> exact v4 -> nu, tau
    if (tid < QB) {
        float a0 = NEGI, a1 = NEGI, a2 = NEGI, a3 = NEGI;
#pragma unroll
        for (int u = 0; u < NW; ++u) {
            float4 v = ldsM[u * QB + tid];
            top4L_insert(v.x, a0, a1, a2, a3);
            top4L_insert(v.y, a0, a1, a2, a3);
            top4L_insert(v.z, a0, a1, a2, a3);
            top4L_insert(v.w, a0, a1, a2, a3);
        }
        float nb = -2.0f * nY[q0 + tid];               // |y|^2
        float nu2 = fmaxf(nb - 2.0f * a3, 1e-12f);     // sq-domain nu^2, clamped
        nusqOut[q0 + tid] = nu2;
        ldsTau[tid] = 0.5f * (nb - nu2);               // s-domain threshold
    }
    __syncthreads();
    float tau[4];
#pragma unroll
    for (int b = 0; b < 4; ++b) tau[b] = ldsTau[q + b * 16];

    // ---------- pass 2: count over X ----------
    int cnt[4] = {0, 0, 0, 0};
    {
        const unsigned short* pH = Xhi + ((size_t)(w * 512) + q) * DIMS + quad * 8;
        const float* pN = nX + w * 512 + quad * 4;
        for (int i = 0; i < 16; ++i) {
            bf16x8 ah0 = *(const bf16x8*)(pH);
            bf16x8 ah1 = *(const bf16x8*)(pH + 16 * DIMS);
            float4 nA0 = *(const float4*)(pN);
            float4 nA1 = *(const float4*)(pN + 16);
            pH += 32 * DIMS; pN += 32;
            f32x4 c0v = {nA0.x, nA0.y, nA0.z, nA0.w};
            f32x4 c1v = {nA1.x, nA1.y, nA1.z, nA1.w};
#pragma unroll
            for (int b = 0; b < 4; ++b) {
                f32x4 a0 = __builtin_amdgcn_mfma_f32_16x16x32_bf16(ah0, bh[b], c0v, 0, 0, 0);
                f32x4 a1 = __builtin_amdgcn_mfma_f32_16x16x32_bf16(ah1, bh[b], c1v, 0, 0, 0);
#pragma unroll
                for (int r = 0; r < 4; ++r) {
                    cnt[b] += (a0[r] >= tau[b]) ? 1 : 0;
                    cnt[b] += (a1[r] >= tau[b]) ? 1 : 0;
                }
            }
        }
    }
    // quad reduce in-register, then [wave][query] LDS
#pragma unroll
    for (int b = 0; b < 4; ++b) {
        int c = cnt[b] + __shfl_xor(cnt[b], 16);
        c += __shfl_xor(c, 32);
        if (quad == 0) ldsC[w * QB + q + b * 16] = c;
    }
    __syncthreads();
    if (tid < QB) {
        int s = 0;
#pragma unroll
        for (int u = 0; u < NW; ++u) s += ldsC[u * QB + tid];
        cntOut[q0 + tid] = s;
        int rsum = s;                                   // block total (wave 0)
        rsum += __shfl_xor(rsum, 1);
        rsum += __shfl_xor(rsum, 2);
        rsum += __shfl_xor(rsum, 4);
        rsum += __shfl_xor(rsum, 8);
        rsum += __shfl_xor(rsum, 16);
        rsum += __shfl_xor(rsum, 32);
        if (tid == 0) atomicAdd(totOut, rsum);          // exact integer sum
    }
}

// K3: epilogue, 16 blocks x 512 thr (one j per thread), last-block-done final reduce.
// Per-block double partials are deterministic (fixed shuffle-tree order); partials are
// published/consumed via device-scope u64 atomics (XCD-L2-coherence safe); the 16th
// finishing block sums all 32 partials in fixed order and writes the output.
__global__ __launch_bounds__(512)
void final_kernel(const int* __restrict__ countP, const int* __restrict__ countQ,
                  const float* __restrict__ nusqP, const float* __restrict__ nusqQ,
                  int* __restrict__ tots, unsigned long long* __restrict__ dparts,
                  float* __restrict__ out) {
    __shared__ double rdQ[8], rdP[8];
    const int tid = threadIdx.x, b = blockIdx.x;
    const int w = tid >> 6, l = tid & 63;
    const int j = b * 512 + tid;

    const float kq_term = 3.0f / 24576.0f;
    float kpQ = (float)tots[1] + 1e-20f;
    float kpP = (float)tots[0] + 1e-20f;
    double rQ, rP;
    {
        float nu = sqrtf(nusqQ[j]);
        float x = nu * nu; x *= x; x *= x; x *= x; x *= x;   // nu^32
        float inv = 1.0f / (x + 1e-20f);
        float p_den = ((float)countQ[j] / kpQ) * inv;
        p_den = fminf(fmaxf(p_den, 1e-20f), 1e10f);
        float q_den = kq_term * inv;
        q_den = fminf(fmaxf(q_den, 1e-20f), 1e10f);
        rQ = (double)((p_den / q_den) * kq_term);
    }
    {
        float nu = sqrtf(nusqP[j]);
        float x = nu * nu; x *= x; x *= x; x *= x; x *= x;
        float inv = 1.0f / (x + 1e-20f);
        float p_den = ((float)countP[j] / kpP) * inv;
        p_den = fminf(fmaxf(p_den, 1e-20f), 1e10f);
        float q_den = kq_term * inv;
        q_den = fminf(fmaxf(q_den, 1e-20f), 1e10f);
        rP = (double)((p_den / q_den) * kq_term);
    }
#pragma unroll
    for (int o = 32; o > 0; o >>= 1) { rQ += __shfl_down(rQ, o); rP += __shfl_down(rP, o); }
    if (l == 0) { rdQ[w] = rQ; rdP[w] = rP; }
    __syncthreads();
    if (tid == 0) {
        double RQ = 0.0, RP = 0.0;
#pragma unroll
        for (int u = 0; u < 8; ++u) { RQ += rdQ[u]; RP += rdP[u]; }
        // publish partials with device-scope atomics, then signal completion
        atomicExch(&dparts[b],      (unsigned long long)__double_as_longlong(RQ));
        atomicExch(&dparts[16 + b], (unsigned long long)__double_as_longlong(RP));
        __threadfence();
        unsigned old = (unsigned)atomicAdd(&tots[2], 1);
        if (old == 15) {                               // last finishing block
            __threadfence();
            double RQt = 0.0, RPt = 0.0;
#pragma unroll
            for (int u = 0; u < 16; ++u)
                RQt += __longlong_as_double((long long)atomicAdd(&dparts[u], 0ULL));
#pragma unroll
            for (int u = 0; u < 16; ++u)
                RPt += __longlong_as_double((long long)atomicAdd(&dparts[16 + u], 0ULL));
            float divP = fmaxf(0.0f, logf((float)RQt));   // alpha=2 -> 1/(alpha-1)=1
            float divQ = fmaxf(0.0f, logf((float)RPt));
            out[0] = fmaxf(divP, divQ);
        }
    }
}

extern "C" void kernel_launch(void* const* d_in, const int* in_sizes, int n_in,
                              void* d_out, int out_size, void* d_ws, size_t ws_size,
                              hipStream_t stream) {
    const float* P = (const float*)d_in[0];
    const float* Q = (const float*)d_in[1];
    float* out = (float*)d_out;

    unsigned short* Phi = (unsigned short*)d_ws;
    unsigned short* Qhi = Phi + MPTS * DIMS;
    float* normP = (float*)(Qhi + MPTS * DIMS);
    float* normQ = normP + MPTS;
    float* nusqP = normQ + MPTS;
    float* nusqQ = nusqP + MPTS;
    int* countP  = (int*)(nusqQ + MPTS);
    int* countQ  = countP + MPTS;
    int* tots    = countQ + MPTS;                     // [0]=sum cP, [1]=sum cQ, [2]=done ctr
    unsigned long long* dparts = (unsigned long long*)(tots + 4);   // 32 slots, 8B aligned

    prep_kernel<<<256, 256, 0, stream>>>(P, Q, Phi, Qhi, normP, normQ, tots);
    fused_kernel<<<dim3(MPTS / QB, 2), 1024, 0, stream>>>(Phi, Qhi, normP, normQ,
                                                          nusqP, nusqQ, countP, countQ, tots);
    final_kernel<<<16, 512, 0, stream>>>(countP, countQ, nusqP, nusqQ, tots, dparts, out);
}

// Round 8
// 101.226 us; speedup vs baseline: 1.1092x; 1.0447x over previous
//
#include <hip/hip_runtime.h>
#include <math.h>

#define MPTS 8192
#define DIMS 32
#define QB   64      // queries per block
#define NW   16      // waves per block (1024 threads)
#define NEGI -3.4e38f

typedef __bf16 bf16x8 __attribute__((ext_vector_type(8)));
typedef float  f32x4  __attribute__((ext_vector_type(4)));

// Insert v into sorted-DESCENDING top-4 (t0>=t1>=t2>=t3): 1 max + 3 med3.
__device__ __forceinline__ void top4L_insert(float v, float& t0, float& t1, float& t2, float& t3) {
    float n0 = fmaxf(t0, v);
    float n1 = __builtin_amdgcn_fmed3f(v, t0, t1);
    float n2 = __builtin_amdgcn_fmed3f(v, t1, t2);
    float n3 = __builtin_amdgcn_fmed3f(v, t2, t3);
    t0 = n0; t1 = n1; t2 = n2; t3 = n3;
}

// Merge two sorted-desc 4-lists -> sorted-desc top-4 (bitonic half-cleaner + merge, 12 ops).
__device__ __forceinline__ void top4_merge(float u0, float u1, float u2, float u3,
                                           float& t0, float& t1, float& t2, float& t3) {
    float m0 = fmaxf(t0, u3), m1 = fmaxf(t1, u2), m2 = fmaxf(t2, u1), m3 = fmaxf(t3, u0);
    float a = fmaxf(m0, m2), c = fminf(m0, m2);
    float b = fmaxf(m1, m3), d = fminf(m1, m3);
    t0 = fmaxf(a, b); t1 = fminf(a, b); t2 = fmaxf(c, d); t3 = fminf(c, d);
}

__device__ __forceinline__ unsigned short f32_to_bf16_rne(float x) {
    unsigned u = __float_as_uint(x);
    unsigned r = u + 0x7FFFu + ((u >> 16) & 1u);
    return (unsigned short)(r >> 16);
}

// K1: bf16 conversion of P,Q + norms pre-scaled by -0.5 ( -|x|^2/2 ). Also zeroes totals.
__global__ void prep_kernel(const float* __restrict__ P, const float* __restrict__ Q,
                            unsigned short* __restrict__ Phi, unsigned short* __restrict__ Qhi,
                            float* __restrict__ normP, float* __restrict__ normQ,
                            int* __restrict__ tots) {
    if (blockIdx.x == 0 && threadIdx.x < 2) tots[threadIdx.x] = 0;
    int t = blockIdx.x * 256 + threadIdx.x;          // 0 .. 65535
    int mat = t >> 15;                               // 0 = P, 1 = Q
    int idx = t & 32767;
    int r = idx >> 2, seg = idx & 3;                 // 8 elements per thread
    const float* X = mat ? Q : P;
    unsigned short* Xhi = mat ? Qhi : Phi;
    float* nX = mat ? normQ : normP;

    const float* src = X + (size_t)r * DIMS + seg * 8;
    float4 v0 = *(const float4*)(src);
    float4 v1 = *(const float4*)(src + 4);
    float f[8] = {v0.x, v0.y, v0.z, v0.w, v1.x, v1.y, v1.z, v1.w};

    float p = 0.f;
#pragma unroll
    for (int k = 0; k < 8; ++k) p = fmaf(f[k], f[k], p);
    p += __shfl_xor(p, 1);
    p += __shfl_xor(p, 2);      // seg groups of 4 are lane-aligned
    if (seg == 0) nX[r] = -0.5f * p;

    unsigned short h[8];
#pragma unroll
    for (int k = 0; k < 8; ++k) h[k] = f32_to_bf16_rne(f[k]);
    uint4 ph;
    ph.x = (unsigned)h[0] | ((unsigned)h[1] << 16);
    ph.y = (unsigned)h[2] | ((unsigned)h[3] << 16);
    ph.z = (unsigned)h[4] | ((unsigned)h[5] << 16);
    ph.w = (unsigned)h[6] | ((unsigned)h[7] << 16);
    *(uint4*)(Xhi + (size_t)r * DIMS + seg * 8) = ph;
}

// K2: fused 2-pass knn+count (best-measured body across 8 rounds: plain loop, global
// norm loads, compiler scheduling — prefetch/unroll/LDS-norms/filter all measured
// neutral-negative). grid (128, 2 dirs), 16 waves, 1 block/CU. Block owns 64 queries;
// lane holds 4 B-frags (queries q+16b) -> 4 top-4 chains. Wave w scans rows
// [w*512,(w+1)*512): per iter 2 row loads feed 8 MFMAs -> 32 inserts.
// s-domain: s = dot - na/2 (larger == closer). Quad-lists merged in-register via
// shfl_xor(16/32) + bitonic merge; pass 2 counts s >= tau; block totals atomicAdd'd.
__global__ __launch_bounds__(1024, 4)
void fused_kernel(const unsigned short* __restrict__ Phi, const unsigned short* __restrict__ Qhi,
                  const float* __restrict__ normP, const float* __restrict__ normQ,
                  float* __restrict__ nusqP, float* __restrict__ nusqQ,
                  int* __restrict__ countP, int* __restrict__ countQ,
                  int* __restrict__ tots) {
    __shared__ float4 ldsM[NW * QB];     // 16 KB: [wave][query] top-4
    __shared__ int    ldsC[NW * QB];     //  4 KB: [wave][query] counts
    __shared__ float  ldsTau[QB];
    const unsigned short *Yhi, *Xhi; const float *nY, *nX; float* nusqOut;
    int* cntOut; int* totOut;
    if (blockIdx.y == 0) { Yhi = Qhi; nY = normQ; Xhi = Phi; nX = normP;
                           nusqOut = nusqQ; cntOut = countQ; totOut = &tots[1]; } // k_p for div_p
    else                 { Yhi = Phi; nY = normP; Xhi = Qhi; nX = normQ;
                           nusqOut = nusqP; cntOut = countP; totOut = &tots[0]; }
    const int tid = threadIdx.x;
    const int w = tid >> 6, l = tid & 63, q = l & 15, quad = l >> 4;
    const int q0 = blockIdx.x * QB;

    // 4 B-frags: query rows q0 + 16*b + q; k-octet = quad
    bf16x8 bh[4];
#pragma unroll
    for (int b = 0; b < 4; ++b)
        bh[b] = *(const bf16x8*)(Yhi + (size_t)(q0 + b * 16 + q) * DIMS + quad * 8);

    // ---------- pass 1: knn over Y ----------
    float t0[4], t1[4], t2[4], t3[4];
#pragma unroll
    for (int b = 0; b < 4; ++b) t0[b] = t1[b] = t2[b] = t3[b] = NEGI;
    {
        const unsigned short* pH = Yhi + ((size_t)(w * 512) + q) * DIMS + quad * 8;
        const float* pN = nY + w * 512 + quad * 4;
        for (int i = 0; i < 16; ++i) {
            bf16x8 ah0 = *(const bf16x8*)(pH);
            bf16x8 ah1 = *(const bf16x8*)(pH + 16 * DIMS);
            float4 nA0 = *(const float4*)(pN);
            float4 nA1 = *(const float4*)(pN + 16);
            pH += 32 * DIMS; pN += 32;
            f32x4 c0v = {nA0.x, nA0.y, nA0.z, nA0.w};
            f32x4 c1v = {nA1.x, nA1.y, nA1.z, nA1.w};
#pragma unroll
            for (int b = 0; b < 4; ++b) {
                f32x4 a0 = __builtin_amdgcn_mfma_f32_16x16x32_bf16(ah0, bh[b], c0v, 0, 0, 0);
                f32x4 a1 = __builtin_amdgcn_mfma_f32_16x16x32_bf16(ah1, bh[b], c1v, 0, 0, 0);
#pragma unroll
                for (int r = 0; r < 4; ++r) top4L_insert(a0[r], t0[b], t1[b], t2[b], t3[b]);
#pragma unroll
                for (int r = 0; r < 4; ++r) top4L_insert(a1[r], t0[b], t1[b], t2[b], t3[b]);
            }
        }
    }
    // in-register quad merge (lanes q, q+16, q+32, q+48 hold disjoint candidate rows)
#pragma unroll
    for (int b = 0; b < 4; ++b) {
        float u0 = __shfl_xor(t0[b], 16), u1 = __shfl_xor(t1[b], 16);
        float u2 = __shfl_xor(t2[b], 16), u3 = __shfl_xor(t3[b], 16);
        top4_merge(u0, u1, u2, u3, t0[b], t1[b], t2[b], t3[b]);
        u0 = __shfl_xor(t0[b], 32); u1 = __shfl_xor(t1[b], 32);
        u2 = __shfl_xor(t2[b], 32); u3 = __shfl_xor(t3[b], 32);
        top4_merge(u0, u1, u2, u3, t0[b], t1[b], t2[b], t3[b]);
        if (quad == 0)
            ldsM[w * QB + q + b * 16] = make_float4(t0[b], t1[b], t2[b], t3[b]);
    }
    __syncthreads();
    // block merge: 16 wave-lists per query -> exact v4 -> nu, tau
    if (tid < QB) {
        float a0 = NEGI, a1 = NEGI, a2 = NEGI, a3 = NEGI;
#pragma unroll
        for (int u = 0; u < NW; ++u) {
            float4 v = ldsM[u * QB + tid];
            top4L_insert(v.x, a0, a1, a2, a3);
            top4L_insert(v.y, a0, a1, a2, a3);
            top4L_insert(v.z, a0, a1, a2, a3);
            top4L_insert(v.w, a0, a1, a2, a3);
        }
        float nb = -2.0f * nY[q0 + tid];               // |y|^2
        float nu2 = fmaxf(nb - 2.0f * a3, 1e-12f);     // sq-domain nu^2, clamped
        nusqOut[q0 + tid] = nu2;
        ldsTau[tid] = 0.5f * (nb - nu2);               // s-domain threshold
    }
    __syncthreads();
    float tau[4];
#pragma unroll
    for (int b = 0; b < 4; ++b) tau[b] = ldsTau[q + b * 16];

    // ---------- pass 2: count over X ----------
    int cnt[4] = {0, 0, 0, 0};
    {
        const unsigned short* pH = Xhi + ((size_t)(w * 512) + q) * DIMS + quad * 8;
        const float* pN = nX + w * 512 + quad * 4;
        for (int i = 0; i < 16; ++i) {
            bf16x8 ah0 = *(const bf16x8*)(pH);
            bf16x8 ah1 = *(const bf16x8*)(pH + 16 * DIMS);
            float4 nA0 = *(const float4*)(pN);
            float4 nA1 = *(const float4*)(pN + 16);
            pH += 32 * DIMS; pN += 32;
            f32x4 c0v = {nA0.x, nA0.y, nA0.z, nA0.w};
            f32x4 c1v = {nA1.x, nA1.y, nA1.z, nA1.w};
#pragma unroll
            for (int b = 0; b < 4; ++b) {
                f32x4 a0 = __builtin_amdgcn_mfma_f32_16x16x32_bf16(ah0, bh[b], c0v, 0, 0, 0);
                f32x4 a1 = __builtin_amdgcn_mfma_f32_16x16x32_bf16(ah1, bh[b], c1v, 0, 0, 0);
#pragma unroll
                for (int r = 0; r < 4; ++r) {
                    cnt[b] += (a0[r] >= tau[b]) ? 1 : 0;
                    cnt[b] += (a1[r] >= tau[b]) ? 1 : 0;
                }
            }
        }
    }
    // quad reduce in-register, then [wave][query] LDS
#pragma unroll
    for (int b = 0; b < 4; ++b) {
        int c = cnt[b] + __shfl_xor(cnt[b], 16);
        c += __shfl_xor(c, 32);
        if (quad == 0) ldsC[w * QB + q + b * 16] = c;
    }
    __syncthreads();
    if (tid < QB) {
        int s = 0;
#pragma unroll
        for (int u = 0; u < NW; ++u) s += ldsC[u * QB + tid];
        cntOut[q0 + tid] = s;
        int rsum = s;                                   // block total (wave 0)
        rsum += __shfl_xor(rsum, 1);
        rsum += __shfl_xor(rsum, 2);
        rsum += __shfl_xor(rsum, 4);
        rsum += __shfl_xor(rsum, 8);
        rsum += __shfl_xor(rsum, 16);
        rsum += __shfl_xor(rsum, 32);
        if (tid == 0) atomicAdd(totOut, rsum);          // exact integer sum
    }
}

// K3a: epilogue partials, 16 blocks x 512 thr (one j per thread). Per-block double
// partial sums are deterministic (fixed shuffle-tree order); written to dparts.
__global__ __launch_bounds__(512)
void final_partial(const int* __restrict__ countP, const int* __restrict__ countQ,
                   const float* __restrict__ nusqP, const float* __restrict__ nusqQ,
                   const int* __restrict__ tots, double* __restrict__ dparts) {
    __shared__ double rdQ[8], rdP[8];
    const int tid = threadIdx.x, b = blockIdx.x;
    const int w = tid >> 6, l = tid & 63;
    const int j = b * 512 + tid;

    const float kq_term = 3.0f / 24576.0f;
    float kpQ = (float)tots[1] + 1e-20f;
    float kpP = (float)tots[0] + 1e-20f;
    double rQ, rP;
    {
        float nu = sqrtf(nusqQ[j]);
        float x = nu * nu; x *= x; x *= x; x *= x; x *= x;   // nu^32
        float inv = 1.0f / (x + 1e-20f);
        float p_den = ((float)countQ[j] / kpQ) * inv;
        p_den = fminf(fmaxf(p_den, 1e-20f), 1e10f);
        float q_den = kq_term * inv;
        q_den = fminf(fmaxf(q_den, 1e-20f), 1e10f);
        rQ = (double)((p_den / q_den) * kq_term);
    }
    {
        float nu = sqrtf(nusqP[j]);
        float x = nu * nu; x *= x; x *= x; x *= x; x *= x;
        float inv = 1.0f / (x + 1e-20f);
        float p_den = ((float)countP[j] / kpP) * inv;
        p_den = fminf(fmaxf(p_den, 1e-20f), 1e10f);
        float q_den = kq_term * inv;
        q_den = fminf(fmaxf(q_den, 1e-20f), 1e10f);
        rP = (double)((p_den / q_den) * kq_term);
    }
#pragma unroll
    for (int o = 32; o > 0; o >>= 1) { rQ += __shfl_down(rQ, o); rP += __shfl_down(rP, o); }
    if (l == 0) { rdQ[w] = rQ; rdP[w] = rP; }
    __syncthreads();
    if (tid == 0) {
        double RQ = 0.0, RP = 0.0;
#pragma unroll
        for (int u = 0; u < 8; ++u) { RQ += rdQ[u]; RP += rdP[u]; }
        dparts[b] = RQ; dparts[16 + b] = RP;
    }
}

// K3b: tiny reduce, fixed summation order.
__global__ void final_reduce(const double* __restrict__ dparts, float* __restrict__ out) {
    if (threadIdx.x == 0) {
        double RQ = 0.0, RP = 0.0;
#pragma unroll
        for (int u = 0; u < 16; ++u) RQ += dparts[u];
#pragma unroll
        for (int u = 0; u < 16; ++u) RP += dparts[16 + u];
        float divP = fmaxf(0.0f, logf((float)RQ));    // alpha=2 -> 1/(alpha-1)=1
        float divQ = fmaxf(0.0f, logf((float)RP));
        out[0] = fmaxf(divP, divQ);
    }
}

extern "C" void kernel_launch(void* const* d_in, const int* in_sizes, int n_in,
                              void* d_out, int out_size, void* d_ws, size_t ws_size,
                              hipStream_t stream) {
    const float* P = (const float*)d_in[0];
    const float* Q = (const float*)d_in[1];
    float* out = (float*)d_out;

    unsigned short* Phi = (unsigned short*)d_ws;
    unsigned short* Qhi = Phi + MPTS * DIMS;
    float* normP = (float*)(Qhi + MPTS * DIMS);
    float* normQ = normP + MPTS;
    float* nusqP = normQ + MPTS;
    float* nusqQ = nusqP + MPTS;
    int* countP  = (int*)(nusqQ + MPTS);
    int* countQ  = countP + MPTS;
    int* tots    = countQ + MPTS;                     // [0]=sum countP, [1]=sum countQ
    double* dparts = (double*)(tots + 2);             // 32 doubles (8B aligned)

    prep_kernel<<<256, 256, 0, stream>>>(P, Q, Phi, Qhi, normP, normQ, tots);
    fused_kernel<<<dim3(MPTS / QB, 2), 1024, 0, stream>>>(Phi, Qhi, normP, normQ,
                                                          nusqP, nusqQ, countP, countQ, tots);
    final_partial<<<16, 512, 0, stream>>>(countP, countQ, nusqP, nusqQ, tots, dparts);
    final_reduce<<<1, 64, 0, stream>>>(dparts, out);
}